// Round 1
// baseline (30215.408 us; speedup 1.0000x reference)
//
#include <hip/hip_runtime.h>
#include <hip/hip_fp16.h>

// ONLSTM fused 2-layer recurrent kernel for MI355X (gfx950).
// Design: single persistent kernel, 256 WGs x 128 thr (1 WG/CU, co-resident),
// layer pipeline (layer0 at t=s, layer1 at t=s-1), fp16 MFMA 16x16x32,
// weights LDS-resident (layer0 full, layer1 h1-half; h0-half streamed from L2),
// custom monotonic-counter grid barriers (2 per super-step, 257 super-steps).

typedef _Float16 f16;
typedef _Float16 f16x8 __attribute__((ext_vector_type(8)));
typedef _Float16 f16x4 __attribute__((ext_vector_type(4)));
typedef float f32x4 __attribute__((ext_vector_type(4)));

#define NWG 256
#define WGL 128

// ---------------- pack kernels ----------------
// B-fragment pack: dst[((w*3+ct)*nkt+kt)*64+lane][8] = W[krow0+kt*32+(lane>>4)*8+i][col]
// col = gate*1024 + w*8 + (lane&7), gate = 2*ct + ((lane&15)>>3)
__global__ void onlstm_pack_w(const float* __restrict__ W, f16* __restrict__ dst,
                              int nkt, int krow0) {
    int idx = blockIdx.x * blockDim.x + threadIdx.x;
    int total = WGL * 3 * nkt * 64;
    if (idx >= total) return;
    int lane = idx & 63;
    int kt = (idx >> 6) % nkt;
    int ct = ((idx >> 6) / nkt) % 3;
    int w  = (idx >> 6) / (nkt * 3);
    int cc = lane & 15;
    int gate = 2 * ct + (cc >> 3);
    int col = gate * 1024 + (w << 3) + (cc & 7);
    int krow = krow0 + kt * 32 + ((lane >> 4) << 3);
    const float* src = W + (size_t)krow * 6144 + col;
    f16x8 v;
#pragma unroll
    for (int i = 0; i < 8; ++i) v[i] = (f16)src[(size_t)i * 6144];
    *(f16x8*)(dst + (size_t)idx * 8) = v;
}

// A-fragment pack of x: dst[((t*16+kt)*4+rt)*64+lane][8] = x[t][rt*16+(lane&15)][kt*32+(lane>>4)*8+i]
__global__ void onlstm_pack_x(const float* __restrict__ x, f16* __restrict__ dst) {
    int idx = blockIdx.x * blockDim.x + threadIdx.x;
    if (idx >= 256 * 16 * 4 * 64) return;
    int lane = idx & 63;
    int rt = (idx >> 6) & 3;
    int kt = (idx >> 8) & 15;
    int t  = idx >> 12;
    int m = rt * 16 + (lane & 15);
    int k = kt * 32 + ((lane >> 4) << 3);
    const float* src = x + ((size_t)t * 64 + m) * 512 + k;
    f16x8 v;
#pragma unroll
    for (int i = 0; i < 8; ++i) v[i] = (f16)src[i];
    *(f16x8*)(dst + (size_t)idx * 8) = v;
}

// ---------------- grid barrier ----------------
__device__ __forceinline__ void gbar(int* __restrict__ B, int idx) {
    __threadfence();              // release: every thread drains its stores to device scope
    __syncthreads();
    if ((threadIdx.x & 63) == 0) {
        if (threadIdx.x == 0)
            __hip_atomic_fetch_add(&B[idx], 1, __ATOMIC_RELEASE, __HIP_MEMORY_SCOPE_AGENT);
        // both wave leaders spin with acquire loads so each wave gets cache-invalidate
        while (__hip_atomic_load(&B[idx], __ATOMIC_ACQUIRE, __HIP_MEMORY_SCOPE_AGENT) < NWG)
            __builtin_amdgcn_s_sleep(2);
    }
    __syncthreads();
}

__device__ __forceinline__ float fast_sigmoid(float x) {
    return 1.0f / (1.0f + __expf(-x));
}
__device__ __forceinline__ float fast_tanh(float x) {
    return 1.0f - 2.0f / (__expf(2.0f * x) + 1.0f);
}

// ---------------- main persistent kernel ----------------
// LDS: sB (B frags, 147456 B max) | sZ 64x49 f32 (12544) | sScl 64x4 (1024) | sBias (256)
__global__ __launch_bounds__(128, 1) void onlstm_main(
    const f16* __restrict__ WB0, const f16* __restrict__ WB1,
    const f16* __restrict__ WS1, const f16* __restrict__ XP,
    f16* __restrict__ H0P, f16* __restrict__ H1P,
    float* __restrict__ PART, int* __restrict__ BARS,
    const float* __restrict__ b0, const float* __restrict__ b1,
    float* __restrict__ out)
{
    extern __shared__ char smem[];
    f16*   sB    = (f16*)smem;
    float* sZ    = (float*)(smem + 147456);
    float* sScl  = (float*)(smem + 147456 + 12544);
    float* sBias = (float*)(smem + 147456 + 12544 + 1024);

    const int tid = threadIdx.x;
    const int wg = blockIdx.x;
    const int layer = wg >> 7;        // 0..1
    const int w = wg & 127;           // j-slice index within layer
    const int lane = tid & 63;
    const int wv = tid >> 6;          // wave id 0..1
    const int j0 = w << 3;
    const int nR = layer ? 32 : 48;   // resident kt count

    // load resident B fragments into LDS
    {
        const float4* s4 = (const float4*)(layer ? (WB1 + (size_t)w * (3 * 32 * 512))
                                                 : (WB0 + (size_t)w * (3 * 48 * 512)));
        float4* d4 = (float4*)sB;
        const int n = 3 * nR * 64;    // 16B chunks
        for (int i = tid; i < n; i += 128) d4[i] = s4[i];
    }
    if (tid < 48) {
        int ct = tid >> 4, r = tid & 15;
        int gate = 2 * ct + (r >> 3);
        const float* bb = layer ? b1 : b0;
        sBias[tid] = bb[gate * 1024 + j0 + (r & 7)];
    }
    // persistent cell state: thread (m = tid&63, jq = tid>>6) owns c[m][j0+jq*4+q]
    float cq0 = 0.f, cq1 = 0.f, cq2 = 0.f, cq3 = 0.f;
    const int m_u = tid & 63;
    const int jq = tid >> 6;
    __syncthreads();

    for (int s = 0; s <= 256; ++s) {
        const int active = layer ? (s >= 1) : (s < 256);
        const int t = layer ? (s - 1) : s;
        const int pr = (s + 1) & 1;   // read parity
        const int pw = s & 1;         // write parity

        if (active) {
            // ---------- GEMM: z[64 x 48] = A[64 x K] * B[K x 48] ----------
            f32x4 acc[2][3];
#pragma unroll
            for (int a = 0; a < 2; ++a)
#pragma unroll
                for (int b_ = 0; b_ < 3; ++b_) { f32x4 z = {0.f, 0.f, 0.f, 0.f}; acc[a][b_] = z; }

            const int rtb = wv << 1;                       // this wave owns rt = rtb, rtb+1
            const size_t aoff = (size_t)(rtb * 512 + lane * 8);

            if (layer == 0) {
                const f16* A1 = XP + (size_t)t * 32768;            // x frags, kt 0..15
                const f16* A2 = H0P + (size_t)pr * 65536;          // h0(t-1), kt 0..31
#pragma unroll 4
                for (int kt = 0; kt < 16; ++kt) {
                    const f16* ap = A1 + (size_t)kt * 2048 + aoff;
                    f16x8 a0 = *(const f16x8*)ap;
                    f16x8 a1 = *(const f16x8*)(ap + 512);
#pragma unroll
                    for (int ct = 0; ct < 3; ++ct) {
                        f16x8 b = *(const f16x8*)(sB + ((size_t)(ct * 48 + kt) * 64 + lane) * 8);
                        acc[0][ct] = __builtin_amdgcn_mfma_f32_16x16x32_f16(a0, b, acc[0][ct], 0, 0, 0);
                        acc[1][ct] = __builtin_amdgcn_mfma_f32_16x16x32_f16(a1, b, acc[1][ct], 0, 0, 0);
                    }
                }
#pragma unroll 4
                for (int kt = 0; kt < 32; ++kt) {
                    const f16* ap = A2 + (size_t)kt * 2048 + aoff;
                    f16x8 a0 = *(const f16x8*)ap;
                    f16x8 a1 = *(const f16x8*)(ap + 512);
#pragma unroll
                    for (int ct = 0; ct < 3; ++ct) {
                        f16x8 b = *(const f16x8*)(sB + ((size_t)(ct * 48 + 16 + kt) * 64 + lane) * 8);
                        acc[0][ct] = __builtin_amdgcn_mfma_f32_16x16x32_f16(a0, b, acc[0][ct], 0, 0, 0);
                        acc[1][ct] = __builtin_amdgcn_mfma_f32_16x16x32_f16(a1, b, acc[1][ct], 0, 0, 0);
                    }
                }
            } else {
                const f16* A1 = H0P + (size_t)pr * 65536;          // h0(t), kt 0..31
                const f16* A2 = H1P + (size_t)pr * 65536;          // h1(t-1), kt 0..31
                const f16* BS = WS1 + (size_t)w * (3 * 32 * 512);  // streamed h0-part weights
#pragma unroll 4
                for (int kt = 0; kt < 32; ++kt) {
                    const f16* ap = A1 + (size_t)kt * 2048 + aoff;
                    f16x8 a0 = *(const f16x8*)ap;
                    f16x8 a1 = *(const f16x8*)(ap + 512);
#pragma unroll
                    for (int ct = 0; ct < 3; ++ct) {
                        f16x8 b = *(const f16x8*)(BS + ((size_t)(ct * 32 + kt) * 64 + lane) * 8);
                        acc[0][ct] = __builtin_amdgcn_mfma_f32_16x16x32_f16(a0, b, acc[0][ct], 0, 0, 0);
                        acc[1][ct] = __builtin_amdgcn_mfma_f32_16x16x32_f16(a1, b, acc[1][ct], 0, 0, 0);
                    }
                }
#pragma unroll 4
                for (int kt = 0; kt < 32; ++kt) {
                    const f16* ap = A2 + (size_t)kt * 2048 + aoff;
                    f16x8 a0 = *(const f16x8*)ap;
                    f16x8 a1 = *(const f16x8*)(ap + 512);
#pragma unroll
                    for (int ct = 0; ct < 3; ++ct) {
                        f16x8 b = *(const f16x8*)(sB + ((size_t)(ct * 32 + kt) * 64 + lane) * 8);
                        acc[0][ct] = __builtin_amdgcn_mfma_f32_16x16x32_f16(a0, b, acc[0][ct], 0, 0, 0);
                        acc[1][ct] = __builtin_amdgcn_mfma_f32_16x16x32_f16(a1, b, acc[1][ct], 0, 0, 0);
                    }
                }
            }
            // epilogue: z (+bias) -> LDS. C/D layout: col = lane&15, row = (lane>>4)*4 + q
            const int mq = ((lane >> 4) << 2);
#pragma unroll
            for (int rt = 0; rt < 2; ++rt) {
                int mrow = (wv << 5) + (rt << 4) + mq;
#pragma unroll
                for (int ct = 0; ct < 3; ++ct) {
                    int col = (ct << 4) + (lane & 15);
                    float bias = sBias[col];
#pragma unroll
                    for (int q = 0; q < 4; ++q)
                        sZ[(mrow + q) * 49 + col] = acc[rt][ct][q] + bias;
                }
            }
        }
        __syncthreads();

        if (active) {
            // ---------- local scan: thread (g=wv, m) does exp + inclusive cumsum over its 8 j ----------
            float run = 0.f;
            int base = m_u * 49 + 32 + (wv << 3);
#pragma unroll
            for (int jj = 0; jj < 8; ++jj) {
                float e = __expf(sZ[base + jj]);
                run += e;
                sZ[base + jj] = run;   // in-place: slot now holds local cumsum
            }
            PART[((size_t)((layer << 1) + wv) * 128 + w) * 64 + m_u] = run;
        }
        gbar(BARS, 2 * s);

        if (active) {
            // ---------- global prefix/total over 128 slices ----------
            const float* pp = PART + (size_t)((layer << 1) + wv) * 8192 + m_u;
            float pref = 0.f, tot = 0.f;
#pragma unroll 8
            for (int w2 = 0; w2 < 128; ++w2) {
                float v = pp[(size_t)w2 << 6];
                tot += v;
                pref += (w2 < w) ? v : 0.f;
            }
            sScl[(m_u << 2) + (wv << 1)] = pref;
            sScl[(m_u << 2) + (wv << 1) + 1] = 1.0f / tot;
        }
        __syncthreads();

        if (active) {
            // ---------- gate math + state update ----------
            float pf = sScl[(m_u << 2) + 0];
            float rf = sScl[(m_u << 2) + 1];
            float pi = sScl[(m_u << 2) + 2];
            float ri = sScl[(m_u << 2) + 3];
            float cq[4] = {cq0, cq1, cq2, cq3};
            float hq[4];
            int zb = m_u * 49;
#pragma unroll
            for (int q = 0; q < 4; ++q) {
                int jj = (jq << 2) + q;
                float zi = sZ[zb + jj];
                float zf = sZ[zb + 8 + jj];
                float zg = sZ[zb + 16 + jj];
                float zo = sZ[zb + 24 + jj];
                float cft = sZ[zb + 32 + jj];
                float cit = sZ[zb + 40 + jj];
                float ftil = (pf + cft) * rf;
                float itil = 1.0f - (pi + cit) * ri;
                float om = ftil * itil;
                float fi = fast_sigmoid(zf);
                float ii = fast_sigmoid(zi);
                float oo = fast_sigmoid(zo);
                float ch = fast_tanh(zg);
                float fh = fi * om + (ftil - om);
                float ih = ii * om + (itil - om);
                float cn = fh * cq[q] + ih * ch;
                cq[q] = cn;
                hq[q] = oo * fast_tanh(cn);
            }
            cq0 = cq[0]; cq1 = cq[1]; cq2 = cq[2]; cq3 = cq[3];

            // publish h as A-fragments (fp16)
            int jfull = j0 + (jq << 2);
            int ktp = jfull >> 5;
            int quad = (jfull >> 3) & 3;
            int i0 = jfull & 7;
            f16* HP = (layer ? H1P : H0P) + (size_t)pw * 65536;
            f16x4 hh;
            hh[0] = (f16)hq[0]; hh[1] = (f16)hq[1]; hh[2] = (f16)hq[2]; hh[3] = (f16)hq[3];
            *(f16x4*)(HP + (((size_t)ktp * 4 + (m_u >> 4)) * 64 + (quad * 16 + (m_u & 15))) * 8 + i0) = hh;

            if (layer) {
                float4 ho = make_float4(hq[0], hq[1], hq[2], hq[3]);
                *(float4*)(out + (size_t)t * 65536 + (size_t)m_u * 1024 + jfull) = ho;
            }
            if (t == 255) {
                float4 ho = make_float4(hq[0], hq[1], hq[2], hq[3]);
                float4 co = make_float4(cq[0], cq[1], cq[2], cq[3]);
                *(float4*)(out + 16777216 + (size_t)layer * 65536 + (size_t)m_u * 1024 + jfull) = ho;
                *(float4*)(out + 16908288 + (size_t)layer * 65536 + (size_t)m_u * 1024 + jfull) = co;
            }
        }
        if (s < 256) gbar(BARS, 2 * s + 1);
    }
}

// ---------------- launch ----------------
extern "C" void kernel_launch(void* const* d_in, const int* in_sizes, int n_in,
                              void* d_out, int out_size, void* d_ws, size_t ws_size,
                              hipStream_t stream) {
    const float* x  = (const float*)d_in[0];
    const float* W0 = (const float*)d_in[1];
    const float* b0 = (const float*)d_in[2];
    const float* W1 = (const float*)d_in[3];
    const float* b1 = (const float*)d_in[4];
    float* out = (float*)d_out;

    char* ws = (char*)d_ws;
    // workspace carve (all 256-aligned); total ~58.6 MB
    f16* WB0   = (f16*)(ws + 0);           // 128*3*48*64*16 = 18874368
    f16* WB1   = (f16*)(ws + 18874368);    // 12582912
    f16* WS1   = (f16*)(ws + 31457280);    // 12582912
    f16* XP    = (f16*)(ws + 44040192);    // 16777216
    f16* H0P   = (f16*)(ws + 60817408);    // 262144
    f16* H1P   = (f16*)(ws + 61079552);    // 262144
    float* PART= (float*)(ws + 61341696);  // 131072
    int* BARS  = (int*)(ws + 61472768);    // 4096

    hipMemsetAsync(H0P, 0, 262144, stream);
    hipMemsetAsync(H1P, 0, 262144, stream);
    hipMemsetAsync(BARS, 0, 4096, stream);

    {   // W0 full (x-part + h-part): resident for layer0
        int n = WGL * 3 * 48 * 64;
        onlstm_pack_w<<<(n + 255) / 256, 256, 0, stream>>>(W0, WB0, 48, 0);
    }
    {   // W1 h1-part (rows 1024..2047): resident for layer1
        int n = WGL * 3 * 32 * 64;
        onlstm_pack_w<<<(n + 255) / 256, 256, 0, stream>>>(W1, WB1, 32, 1024);
    }
    {   // W1 h0-part (rows 0..1023): streamed
        int n = WGL * 3 * 32 * 64;
        onlstm_pack_w<<<(n + 255) / 256, 256, 0, stream>>>(W1, WS1, 32, 0);
    }
    {   // x -> A fragments
        int n = 256 * 16 * 4 * 64;
        onlstm_pack_x<<<(n + 255) / 256, 256, 0, stream>>>(x, XP);
    }

    const int smem_bytes = 147456 + 12544 + 1024 + 256;  // 161280 <= 163840
    hipFuncSetAttribute((const void*)onlstm_main,
                        hipFuncAttributeMaxDynamicSharedMemorySize, smem_bytes);
    onlstm_main<<<NWG, 128, smem_bytes, stream>>>(WB0, WB1, WS1, XP, H0P, H1P,
                                                  PART, BARS, b0, b1, out);
}

// Round 2
// 12235.476 us; speedup vs baseline: 2.4695x; 2.4695x over previous
//
#include <hip/hip_runtime.h>
#include <hip/hip_fp16.h>

// ONLSTM fused 2-layer recurrent kernel for MI355X (gfx950), round 2.
// Changes vs r1: contention-free per-WG flag barriers (no atomic RMW),
// layer-split barriers with pipeline slack (H0P triple-buffered),
// 256-thread WGs (4 waves -> 4 SIMDs), K-split GEMM with LDS atomic-add
// epilogue, half-split global prefix loop.

typedef _Float16 f16;
typedef _Float16 f16x8 __attribute__((ext_vector_type(8)));
typedef _Float16 f16x2 __attribute__((ext_vector_type(2)));
typedef float f32x4 __attribute__((ext_vector_type(4)));

#define NWG 256
#define AGENT __HIP_MEMORY_SCOPE_AGENT

// ---------------- pack kernels (unchanged layouts from r1, verified) ----------------
__global__ void onlstm_pack_w(const float* __restrict__ W, f16* __restrict__ dst,
                              int nkt, int krow0) {
    int idx = blockIdx.x * blockDim.x + threadIdx.x;
    int total = 128 * 3 * nkt * 64;
    if (idx >= total) return;
    int lane = idx & 63;
    int kt = (idx >> 6) % nkt;
    int ct = ((idx >> 6) / nkt) % 3;
    int w  = (idx >> 6) / (nkt * 3);
    int cc = lane & 15;
    int gate = 2 * ct + (cc >> 3);
    int col = gate * 1024 + (w << 3) + (cc & 7);
    int krow = krow0 + kt * 32 + ((lane >> 4) << 3);
    const float* src = W + (size_t)krow * 6144 + col;
    f16x8 v;
#pragma unroll
    for (int i = 0; i < 8; ++i) v[i] = (f16)src[(size_t)i * 6144];
    *(f16x8*)(dst + (size_t)idx * 8) = v;
}

__global__ void onlstm_pack_x(const float* __restrict__ x, f16* __restrict__ dst) {
    int idx = blockIdx.x * blockDim.x + threadIdx.x;
    if (idx >= 256 * 16 * 4 * 64) return;
    int lane = idx & 63;
    int rt = (idx >> 6) & 3;
    int kt = (idx >> 8) & 15;
    int t  = idx >> 12;
    int m = rt * 16 + (lane & 15);
    int k = kt * 32 + ((lane >> 4) << 3);
    const float* src = x + ((size_t)t * 64 + m) * 512 + k;
    f16x8 v;
#pragma unroll
    for (int i = 0; i < 8; ++i) v[i] = (f16)src[i];
    *(f16x8*)(dst + (size_t)idx * 8) = v;
}

__device__ __forceinline__ float fast_sigmoid(float x) {
    return 1.0f / (1.0f + __expf(-x));
}
__device__ __forceinline__ float fast_tanh(float x) {
    return 1.0f - 2.0f / (__expf(2.0f * x) + 1.0f);
}

// ---------------- main persistent kernel ----------------
// LDS: sB 147456 | sZ 64x49 f32 12544 | sPfx 2048 | sScl 1024 | sBias 256  = 163328
__global__ __launch_bounds__(256, 1) void onlstm_main(
    const f16* __restrict__ WB0, const f16* __restrict__ WB1,
    const f16* __restrict__ WS1, const f16* __restrict__ XP,
    f16* __restrict__ H0P, f16* __restrict__ H1P,
    float* __restrict__ PART, int* __restrict__ FLAGS,
    const float* __restrict__ b0, const float* __restrict__ b1,
    float* __restrict__ out)
{
    extern __shared__ char smem[];
    f16*   sB    = (f16*)smem;
    float* sZ    = (float*)(smem + 147456);
    float* sPfx  = (float*)(smem + 160000);
    float* sScl  = (float*)(smem + 162048);
    float* sBias = (float*)(smem + 163072);

    const int tid = threadIdx.x;
    const int wg = blockIdx.x;
    const int layer = wg >> 7;
    const int w = wg & 127;
    const int lane = tid & 63;
    const int wv = tid >> 6;          // 0..3
    const int rtp = wv & 1;           // row-pair (rows rtp*32 .. rtp*32+31)
    const int kh = wv >> 1;           // K-half
    const int j0 = w << 3;
    const int m_u = tid & 63;
    const int pr4 = tid >> 6;
    int* FA = FLAGS;                  // barrier-A flags, stride 16 ints (64B)
    int* FB = FLAGS + 4096;           // barrier-B flags

    // resident weights -> LDS
    {
        const float4* s4 = (const float4*)(layer ? (WB1 + (size_t)w * (3 * 32 * 512))
                                                 : (WB0 + (size_t)w * (3 * 48 * 512)));
        float4* d4 = (float4*)sB;
        const int n = layer ? (3 * 32 * 64) : (3 * 48 * 64);
        for (int i = tid; i < n; i += 256) d4[i] = s4[i];
    }
    if (tid < 48) {
        int ct = tid >> 4, r = tid & 15;
        int gate = 2 * ct + (r >> 3);
        sBias[tid] = (layer ? b1 : b0)[gate * 1024 + j0 + (r & 7)];
    }
    float c0 = 0.f, c1 = 0.f;   // persistent cell state: (m_u, j0 + pr4*2 + {0,1})
    __syncthreads();

    for (int s = 0; s <= 256; ++s) {
        const int active = layer ? (s >= 1) : (s < 256);
        const int t = layer ? (s - 1) : s;
        const int hr = (s + 2) % 3;               // H0 read slot = h0(s-1)

        if (active) {
            // init sZ with bias (each thread: 1 row, 12 cols)
            int m = tid >> 2, cb = (tid & 3) * 12;
            float* dst = sZ + m * 49 + cb;
            const float* bsrc = sBias + cb;
#pragma unroll
            for (int k = 0; k < 12; ++k) dst[k] = bsrc[k];
        }
        __syncthreads();

        if (active) {
            // ---------- GEMM (K-split across wave pairs) ----------
            f32x4 acc[2][3];
#pragma unroll
            for (int r = 0; r < 2; ++r)
#pragma unroll
                for (int c = 0; c < 3; ++c) { f32x4 z = {0.f,0.f,0.f,0.f}; acc[r][c] = z; }

            const f16* h0r = H0P + (size_t)hr * 65536;
            const int abase = rtp * 1024 + lane * 8;

            if (layer == 0) {
                if (kh == 0) {
                    const f16* A1 = XP + (size_t)t * 32768;
#pragma unroll 8
                    for (int kt = 0; kt < 16; ++kt) {
                        const f16* ap = A1 + (size_t)kt * 2048 + abase;
                        f16x8 a0 = *(const f16x8*)ap;
                        f16x8 a1 = *(const f16x8*)(ap + 512);
#pragma unroll
                        for (int ct = 0; ct < 3; ++ct) {
                            f16x8 b = *(const f16x8*)(sB + ((size_t)(ct * 48 + kt) * 64 + lane) * 8);
                            acc[0][ct] = __builtin_amdgcn_mfma_f32_16x16x32_f16(a0, b, acc[0][ct], 0, 0, 0);
                            acc[1][ct] = __builtin_amdgcn_mfma_f32_16x16x32_f16(a1, b, acc[1][ct], 0, 0, 0);
                        }
                    }
#pragma unroll 8
                    for (int kt = 0; kt < 8; ++kt) {
                        const f16* ap = h0r + (size_t)kt * 2048 + abase;
                        f16x8 a0 = *(const f16x8*)ap;
                        f16x8 a1 = *(const f16x8*)(ap + 512);
#pragma unroll
                        for (int ct = 0; ct < 3; ++ct) {
                            f16x8 b = *(const f16x8*)(sB + ((size_t)(ct * 48 + 16 + kt) * 64 + lane) * 8);
                            acc[0][ct] = __builtin_amdgcn_mfma_f32_16x16x32_f16(a0, b, acc[0][ct], 0, 0, 0);
                            acc[1][ct] = __builtin_amdgcn_mfma_f32_16x16x32_f16(a1, b, acc[1][ct], 0, 0, 0);
                        }
                    }
                } else {
#pragma unroll 8
                    for (int kt = 8; kt < 32; ++kt) {
                        const f16* ap = h0r + (size_t)kt * 2048 + abase;
                        f16x8 a0 = *(const f16x8*)ap;
                        f16x8 a1 = *(const f16x8*)(ap + 512);
#pragma unroll
                        for (int ct = 0; ct < 3; ++ct) {
                            f16x8 b = *(const f16x8*)(sB + ((size_t)(ct * 48 + 16 + kt) * 64 + lane) * 8);
                            acc[0][ct] = __builtin_amdgcn_mfma_f32_16x16x32_f16(a0, b, acc[0][ct], 0, 0, 0);
                            acc[1][ct] = __builtin_amdgcn_mfma_f32_16x16x32_f16(a1, b, acc[1][ct], 0, 0, 0);
                        }
                    }
                }
            } else {
                if (kh == 0) {
                    const f16* BS = WS1 + (size_t)w * (3 * 32 * 512);  // streamed (L3)
#pragma unroll 8
                    for (int kt = 0; kt < 32; ++kt) {
                        const f16* ap = h0r + (size_t)kt * 2048 + abase;
                        f16x8 a0 = *(const f16x8*)ap;
                        f16x8 a1 = *(const f16x8*)(ap + 512);
#pragma unroll
                        for (int ct = 0; ct < 3; ++ct) {
                            f16x8 b = *(const f16x8*)(BS + ((size_t)(ct * 32 + kt) * 64 + lane) * 8);
                            acc[0][ct] = __builtin_amdgcn_mfma_f32_16x16x32_f16(a0, b, acc[0][ct], 0, 0, 0);
                            acc[1][ct] = __builtin_amdgcn_mfma_f32_16x16x32_f16(a1, b, acc[1][ct], 0, 0, 0);
                        }
                    }
                } else {
                    const f16* h1r = H1P + (size_t)(s & 1) * 65536;    // h1(s-2)
#pragma unroll 8
                    for (int kt = 0; kt < 32; ++kt) {
                        const f16* ap = h1r + (size_t)kt * 2048 + abase;
                        f16x8 a0 = *(const f16x8*)ap;
                        f16x8 a1 = *(const f16x8*)(ap + 512);
#pragma unroll
                        for (int ct = 0; ct < 3; ++ct) {
                            f16x8 b = *(const f16x8*)(sB + ((size_t)(ct * 32 + kt) * 64 + lane) * 8);
                            acc[0][ct] = __builtin_amdgcn_mfma_f32_16x16x32_f16(a0, b, acc[0][ct], 0, 0, 0);
                            acc[1][ct] = __builtin_amdgcn_mfma_f32_16x16x32_f16(a1, b, acc[1][ct], 0, 0, 0);
                        }
                    }
                }
            }
            // epilogue: accumulate partial sums into sZ (bias pre-loaded)
            const int mq = ((lane >> 4) << 2);
            const int colb = lane & 15;
#pragma unroll
            for (int r = 0; r < 2; ++r) {
                int mrow = rtp * 32 + r * 16 + mq;
#pragma unroll
                for (int ct = 0; ct < 3; ++ct) {
                    int col = ct * 16 + colb;
#pragma unroll
                    for (int q = 0; q < 4; ++q)
                        atomicAdd(&sZ[(mrow + q) * 49 + col], acc[r][ct][q]);
                }
            }
        }
        __syncthreads();

        if (active && tid < 128) {
            // local scan: exp + inclusive cumsum over 8 cols (g=f~ or i~)
            int g = tid >> 6, m = tid & 63;
            float run = 0.f;
            float* zp = sZ + m * 49 + 32 + g * 8;
#pragma unroll
            for (int jj = 0; jj < 8; ++jj) {
                float e = __expf(zp[jj]);
                run += e;
                zp[jj] = run;
            }
            PART[((size_t)(layer * 2 + g) * 128 + w) * 64 + m] = run;
        }

        // ---------- barrier A (layer-local, flag-based) ----------
        __syncthreads();
        if (tid == 0)
            __hip_atomic_store(&FA[wg * 16], s + 1, __ATOMIC_RELEASE, AGENT);
        if (tid < 128) {
            const int* fp = &FA[(layer * 128 + tid) * 16];
            while (__hip_atomic_load(fp, __ATOMIC_RELAXED, AGENT) < s + 1) {}
        }
        __builtin_amdgcn_fence(__ATOMIC_ACQUIRE, "agent");
        __syncthreads();

        if (active) {
            // global prefix/total, half-split across the 4 waves
            int g = pr4 & 1, half = pr4 >> 1;
            const float* pp = PART + ((size_t)(layer * 2 + g) * 128 + half * 64) * 64 + m_u;
            float pref = 0.f, tot = 0.f;
            int wrel = w - half * 64;
#pragma unroll 16
            for (int w2 = 0; w2 < 64; ++w2) {
                float v = pp[(size_t)w2 * 64];
                tot += v;
                pref += (w2 < wrel) ? v : 0.f;
            }
            float* q = sPfx + ((size_t)(m_u * 2 + g) * 2 + half) * 2;
            q[0] = pref; q[1] = tot;
        }
        __syncthreads();
        if (active && tid < 128) {
            int g = tid >> 6, m = tid & 63;
            float* q = sPfx + (size_t)(m * 2 + g) * 4;
            sScl[m * 4 + g * 2]     = q[0] + q[2];
            sScl[m * 4 + g * 2 + 1] = 1.0f / (q[1] + q[3]);
        }
        __syncthreads();

        if (active) {
            // ---------- gate math + state update (2 cols/thread) ----------
            float pf = sScl[m_u * 4 + 0], rf = sScl[m_u * 4 + 1];
            float pi = sScl[m_u * 4 + 2], ri = sScl[m_u * 4 + 3];
            int zb = m_u * 49;
            float cc[2] = {c0, c1}, hh[2];
#pragma unroll
            for (int q = 0; q < 2; ++q) {
                int jj = pr4 * 2 + q;
                float zi = sZ[zb + jj];
                float zf = sZ[zb + 8 + jj];
                float zg = sZ[zb + 16 + jj];
                float zo = sZ[zb + 24 + jj];
                float cft = sZ[zb + 32 + jj];
                float cit = sZ[zb + 40 + jj];
                float ftil = (pf + cft) * rf;
                float itil = 1.0f - (pi + cit) * ri;
                float om = ftil * itil;
                float fi = fast_sigmoid(zf);
                float ii = fast_sigmoid(zi);
                float oo = fast_sigmoid(zo);
                float ch = fast_tanh(zg);
                float fh = fi * om + (ftil - om);
                float ih = ii * om + (itil - om);
                float cn = fh * cc[q] + ih * ch;
                cc[q] = cn;
                hh[q] = oo * fast_tanh(cn);
            }
            c0 = cc[0]; c1 = cc[1];

            // publish h as A-fragments (fp16)
            int jfull = j0 + pr4 * 2;
            int ktp = jfull >> 5;
            int quad = (jfull >> 3) & 3;
            int i0 = jfull & 7;
            f16* HP = layer ? (H1P + (size_t)((s + 1) & 1) * 65536)
                            : (H0P + (size_t)(s % 3) * 65536);
            f16x2 hv; hv[0] = (f16)hh[0]; hv[1] = (f16)hh[1];
            *(f16x2*)(HP + ((size_t)(ktp * 4 + (m_u >> 4)) * 64 + (quad * 16 + (m_u & 15))) * 8 + i0) = hv;

            if (layer)
                *(float2*)(out + (size_t)t * 65536 + (size_t)m_u * 1024 + jfull) = make_float2(hh[0], hh[1]);
            if (t == 255) {
                *(float2*)(out + 16777216 + (size_t)layer * 65536 + (size_t)m_u * 1024 + jfull) = make_float2(hh[0], hh[1]);
                *(float2*)(out + 16908288 + (size_t)layer * 65536 + (size_t)m_u * 1024 + jfull) = make_float2(cc[0], cc[1]);
            }
        }

        // ---------- barrier B (split by layer, with pipeline slack) ----------
        if (s < 256) {
            __syncthreads();
            if (tid == 0)
                __hip_atomic_store(&FB[wg * 16], s + 1, __ATOMIC_RELEASE, AGENT);
            if (layer == 0) {
                if (tid < 128) {
                    // need all h0(s) published before next GEMM
                    const int* fp = &FB[tid * 16];
                    while (__hip_atomic_load(fp, __ATOMIC_RELAXED, AGENT) < s + 1) {}
                } else {
                    // anti-overwrite: layer1 must have finished GEMM of step s-1
                    // (its barrier-A arrival value s) before we overwrite slot (s+1)%3
                    const int* fp = &FA[tid * 16];   // tid 128..255 -> layer1 flags
                    while (__hip_atomic_load(fp, __ATOMIC_RELAXED, AGENT) < s) {}
                }
            } else {
                // need h0(s) (flags 0..127) and h1(s-1) (flags 128..255)
                const int* fp = &FB[tid * 16];
                while (__hip_atomic_load(fp, __ATOMIC_RELAXED, AGENT) < s + 1) {}
            }
            __builtin_amdgcn_fence(__ATOMIC_ACQUIRE, "agent");
            __syncthreads();
        }
    }
}

// ---------------- launch ----------------
extern "C" void kernel_launch(void* const* d_in, const int* in_sizes, int n_in,
                              void* d_out, int out_size, void* d_ws, size_t ws_size,
                              hipStream_t stream) {
    const float* x  = (const float*)d_in[0];
    const float* W0 = (const float*)d_in[1];
    const float* b0 = (const float*)d_in[2];
    const float* W1 = (const float*)d_in[3];
    const float* b1 = (const float*)d_in[4];
    float* out = (float*)d_out;

    char* ws = (char*)d_ws;
    f16* WB0    = (f16*)(ws + 0);           // 18874368
    f16* WB1    = (f16*)(ws + 18874368);    // 12582912
    f16* WS1    = (f16*)(ws + 31457280);    // 12582912
    f16* XP     = (f16*)(ws + 44040192);    // 16777216
    f16* H0P    = (f16*)(ws + 60817408);    // 3 slots x 131072 = 393216
    f16* H1P    = (f16*)(ws + 61210624);    // 2 slots x 131072 = 262144
    float* PART = (float*)(ws + 61472768);  // 131072
    int* FLAGS  = (int*)(ws + 61603840);    // 32768 (FA 16KB + FB 16KB)

    hipMemsetAsync(H0P, 0, 393216, stream);
    hipMemsetAsync(H1P, 0, 262144, stream);
    hipMemsetAsync(FLAGS, 0, 32768, stream);

    {   int n = 128 * 3 * 48 * 64;
        onlstm_pack_w<<<(n + 255) / 256, 256, 0, stream>>>(W0, WB0, 48, 0); }
    {   int n = 128 * 3 * 32 * 64;
        onlstm_pack_w<<<(n + 255) / 256, 256, 0, stream>>>(W1, WB1, 32, 1024); }
    {   int n = 128 * 3 * 32 * 64;
        onlstm_pack_w<<<(n + 255) / 256, 256, 0, stream>>>(W1, WS1, 32, 0); }
    {   int n = 256 * 16 * 4 * 64;
        onlstm_pack_x<<<(n + 255) / 256, 256, 0, stream>>>(x, XP); }

    const int smem_bytes = 163328;
    hipFuncSetAttribute((const void*)onlstm_main,
                        hipFuncAttributeMaxDynamicSharedMemorySize, smem_bytes);
    onlstm_main<<<NWG, 256, smem_bytes, stream>>>(WB0, WB1, WS1, XP, H0P, H1P,
                                                  PART, FLAGS, b0, b1, out);
}

// Round 3
// 5918.458 us; speedup vs baseline: 5.1053x; 2.0673x over previous
//
#include <hip/hip_runtime.h>
#include <hip/hip_fp16.h>

// ONLSTM fused 2-layer recurrent kernel for MI355X (gfx950), round 3.
// Change vs r2: ZERO fences in the steady-state loop. All cross-WG data
// (h fragments, PART, flags) moves via relaxed agent-scope atomics (sc1,
// L2-bypassing write-through stores / coherent loads). __syncthreads()'s
// implicit vmcnt(0) orders data stores before flag publication. This removes
// the per-barrier buffer_wbl2/buffer_inv L2 walks that dominated r2
// (~47 us/step with <2 MB/step of actual traffic).

typedef _Float16 f16;
typedef _Float16 f16x8 __attribute__((ext_vector_type(8)));
typedef _Float16 f16x2 __attribute__((ext_vector_type(2)));
typedef float f32x4 __attribute__((ext_vector_type(4)));

#define NWG 256
#define AGENT __HIP_MEMORY_SCOPE_AGENT

// coherent (sc1) 16B fragment load: two relaxed agent-scope u64 atomic loads
__device__ __forceinline__ f16x8 ld_frag(const f16* p) {
    union { unsigned long long u[2]; f16x8 v; } c;
    c.u[0] = __hip_atomic_load((const unsigned long long*)p, __ATOMIC_RELAXED, AGENT);
    c.u[1] = __hip_atomic_load(((const unsigned long long*)p) + 1, __ATOMIC_RELAXED, AGENT);
    return c.v;
}

// ---------------- pack kernels (unchanged, verified) ----------------
__global__ void onlstm_pack_w(const float* __restrict__ W, f16* __restrict__ dst,
                              int nkt, int krow0) {
    int idx = blockIdx.x * blockDim.x + threadIdx.x;
    int total = 128 * 3 * nkt * 64;
    if (idx >= total) return;
    int lane = idx & 63;
    int kt = (idx >> 6) % nkt;
    int ct = ((idx >> 6) / nkt) % 3;
    int w  = (idx >> 6) / (nkt * 3);
    int cc = lane & 15;
    int gate = 2 * ct + (cc >> 3);
    int col = gate * 1024 + (w << 3) + (cc & 7);
    int krow = krow0 + kt * 32 + ((lane >> 4) << 3);
    const float* src = W + (size_t)krow * 6144 + col;
    f16x8 v;
#pragma unroll
    for (int i = 0; i < 8; ++i) v[i] = (f16)src[(size_t)i * 6144];
    *(f16x8*)(dst + (size_t)idx * 8) = v;
}

__global__ void onlstm_pack_x(const float* __restrict__ x, f16* __restrict__ dst) {
    int idx = blockIdx.x * blockDim.x + threadIdx.x;
    if (idx >= 256 * 16 * 4 * 64) return;
    int lane = idx & 63;
    int rt = (idx >> 6) & 3;
    int kt = (idx >> 8) & 15;
    int t  = idx >> 12;
    int m = rt * 16 + (lane & 15);
    int k = kt * 32 + ((lane >> 4) << 3);
    const float* src = x + ((size_t)t * 64 + m) * 512 + k;
    f16x8 v;
#pragma unroll
    for (int i = 0; i < 8; ++i) v[i] = (f16)src[i];
    *(f16x8*)(dst + (size_t)idx * 8) = v;
}

__device__ __forceinline__ float fast_sigmoid(float x) {
    return 1.0f / (1.0f + __expf(-x));
}
__device__ __forceinline__ float fast_tanh(float x) {
    return 1.0f - 2.0f / (__expf(2.0f * x) + 1.0f);
}

// ---------------- main persistent kernel ----------------
// LDS: sB 147456 | sZ 64x49 f32 12544 | sPfx 2048 | sScl 1024 | sBias 256
__global__ __launch_bounds__(256, 1) void onlstm_main(
    const f16* __restrict__ WB0, const f16* __restrict__ WB1,
    const f16* __restrict__ WS1, const f16* __restrict__ XP,
    f16* __restrict__ H0P, f16* __restrict__ H1P,
    float* __restrict__ PART, int* __restrict__ FLAGS,
    const float* __restrict__ b0, const float* __restrict__ b1,
    float* __restrict__ out)
{
    extern __shared__ char smem[];
    f16*   sB    = (f16*)smem;
    float* sZ    = (float*)(smem + 147456);
    float* sPfx  = (float*)(smem + 160000);
    float* sScl  = (float*)(smem + 162048);
    float* sBias = (float*)(smem + 163072);

    const int tid = threadIdx.x;
    const int wg = blockIdx.x;
    const int layer = wg >> 7;
    const int w = wg & 127;
    const int lane = tid & 63;
    const int wv = tid >> 6;          // 0..3
    const int rtp = wv & 1;           // row-pair
    const int kh = wv >> 1;           // K-half
    const int j0 = w << 3;
    const int m_u = tid & 63;
    const int pr4 = tid >> 6;
    int* FA = FLAGS;                  // barrier-A flags, stride 16 ints (64B)
    int* FB = FLAGS + 4096;           // barrier-B flags

    // resident weights -> LDS (pre-kernel data: normal cached loads are safe)
    {
        const float4* s4 = (const float4*)(layer ? (WB1 + (size_t)w * (3 * 32 * 512))
                                                 : (WB0 + (size_t)w * (3 * 48 * 512)));
        float4* d4 = (float4*)sB;
        const int n = layer ? (3 * 32 * 64) : (3 * 48 * 64);
        for (int i = tid; i < n; i += 256) d4[i] = s4[i];
    }
    if (tid < 48) {
        int ct = tid >> 4, r = tid & 15;
        int gate = 2 * ct + (r >> 3);
        sBias[tid] = (layer ? b1 : b0)[gate * 1024 + j0 + (r & 7)];
    }
    float c0 = 0.f, c1 = 0.f;   // persistent cell state: (m_u, j0 + pr4*2 + {0,1})
    __syncthreads();

    for (int s = 0; s <= 256; ++s) {
        const int active = layer ? (s >= 1) : (s < 256);
        const int t = layer ? (s - 1) : s;
        const int hr = (s + 2) % 3;               // H0 read slot = h0(s-1)

        if (active) {
            // init sZ with bias
            int m = tid >> 2, cb = (tid & 3) * 12;
            float* dst = sZ + m * 49 + cb;
            const float* bsrc = sBias + cb;
#pragma unroll
            for (int k = 0; k < 12; ++k) dst[k] = bsrc[k];
        }
        __syncthreads();

        if (active) {
            // ---------- GEMM (K-split across wave pairs) ----------
            f32x4 acc[2][3];
#pragma unroll
            for (int r = 0; r < 2; ++r)
#pragma unroll
                for (int c = 0; c < 3; ++c) { f32x4 z = {0.f,0.f,0.f,0.f}; acc[r][c] = z; }

            const f16* h0r = H0P + (size_t)hr * 65536;
            const int abase = rtp * 1024 + lane * 8;

            if (layer == 0) {
                if (kh == 0) {
                    const f16* A1 = XP + (size_t)t * 32768;
#pragma unroll 8
                    for (int kt = 0; kt < 16; ++kt) {
                        const f16* ap = A1 + (size_t)kt * 2048 + abase;
                        f16x8 a0 = *(const f16x8*)ap;          // XP: pre-kernel, cached
                        f16x8 a1 = *(const f16x8*)(ap + 512);
#pragma unroll
                        for (int ct = 0; ct < 3; ++ct) {
                            f16x8 b = *(const f16x8*)(sB + ((size_t)(ct * 48 + kt) * 64 + lane) * 8);
                            acc[0][ct] = __builtin_amdgcn_mfma_f32_16x16x32_f16(a0, b, acc[0][ct], 0, 0, 0);
                            acc[1][ct] = __builtin_amdgcn_mfma_f32_16x16x32_f16(a1, b, acc[1][ct], 0, 0, 0);
                        }
                    }
#pragma unroll 8
                    for (int kt = 0; kt < 8; ++kt) {
                        const f16* ap = h0r + (size_t)kt * 2048 + abase;
                        f16x8 a0 = ld_frag(ap);                // H: intra-kernel, sc1
                        f16x8 a1 = ld_frag(ap + 512);
#pragma unroll
                        for (int ct = 0; ct < 3; ++ct) {
                            f16x8 b = *(const f16x8*)(sB + ((size_t)(ct * 48 + 16 + kt) * 64 + lane) * 8);
                            acc[0][ct] = __builtin_amdgcn_mfma_f32_16x16x32_f16(a0, b, acc[0][ct], 0, 0, 0);
                            acc[1][ct] = __builtin_amdgcn_mfma_f32_16x16x32_f16(a1, b, acc[1][ct], 0, 0, 0);
                        }
                    }
                } else {
#pragma unroll 8
                    for (int kt = 8; kt < 32; ++kt) {
                        const f16* ap = h0r + (size_t)kt * 2048 + abase;
                        f16x8 a0 = ld_frag(ap);
                        f16x8 a1 = ld_frag(ap + 512);
#pragma unroll
                        for (int ct = 0; ct < 3; ++ct) {
                            f16x8 b = *(const f16x8*)(sB + ((size_t)(ct * 48 + 16 + kt) * 64 + lane) * 8);
                            acc[0][ct] = __builtin_amdgcn_mfma_f32_16x16x32_f16(a0, b, acc[0][ct], 0, 0, 0);
                            acc[1][ct] = __builtin_amdgcn_mfma_f32_16x16x32_f16(a1, b, acc[1][ct], 0, 0, 0);
                        }
                    }
                }
            } else {
                if (kh == 0) {
                    const f16* BS = WS1 + (size_t)w * (3 * 32 * 512);  // pre-kernel, cached
#pragma unroll 8
                    for (int kt = 0; kt < 32; ++kt) {
                        const f16* ap = h0r + (size_t)kt * 2048 + abase;
                        f16x8 a0 = ld_frag(ap);
                        f16x8 a1 = ld_frag(ap + 512);
#pragma unroll
                        for (int ct = 0; ct < 3; ++ct) {
                            f16x8 b = *(const f16x8*)(BS + ((size_t)(ct * 32 + kt) * 64 + lane) * 8);
                            acc[0][ct] = __builtin_amdgcn_mfma_f32_16x16x32_f16(a0, b, acc[0][ct], 0, 0, 0);
                            acc[1][ct] = __builtin_amdgcn_mfma_f32_16x16x32_f16(a1, b, acc[1][ct], 0, 0, 0);
                        }
                    }
                } else {
                    const f16* h1r = H1P + (size_t)(s & 1) * 65536;    // h1(s-2)
#pragma unroll 8
                    for (int kt = 0; kt < 32; ++kt) {
                        const f16* ap = h1r + (size_t)kt * 2048 + abase;
                        f16x8 a0 = ld_frag(ap);
                        f16x8 a1 = ld_frag(ap + 512);
#pragma unroll
                        for (int ct = 0; ct < 3; ++ct) {
                            f16x8 b = *(const f16x8*)(sB + ((size_t)(ct * 32 + kt) * 64 + lane) * 8);
                            acc[0][ct] = __builtin_amdgcn_mfma_f32_16x16x32_f16(a0, b, acc[0][ct], 0, 0, 0);
                            acc[1][ct] = __builtin_amdgcn_mfma_f32_16x16x32_f16(a1, b, acc[1][ct], 0, 0, 0);
                        }
                    }
                }
            }
            // epilogue: accumulate partials into sZ (bias pre-loaded)
            const int mq = ((lane >> 4) << 2);
            const int colb = lane & 15;
#pragma unroll
            for (int r = 0; r < 2; ++r) {
                int mrow = rtp * 32 + r * 16 + mq;
#pragma unroll
                for (int ct = 0; ct < 3; ++ct) {
                    int col = ct * 16 + colb;
#pragma unroll
                    for (int q = 0; q < 4; ++q)
                        atomicAdd(&sZ[(mrow + q) * 49 + col], acc[r][ct][q]);
                }
            }
        }
        __syncthreads();

        if (active && tid < 128) {
            // local scan: exp + inclusive cumsum over 8 cols (g = f~ or i~)
            int g = tid >> 6, m = tid & 63;
            float run = 0.f;
            float* zp = sZ + m * 49 + 32 + g * 8;
#pragma unroll
            for (int jj = 0; jj < 8; ++jj) {
                float e = __expf(zp[jj]);
                run += e;
                zp[jj] = run;
            }
            __hip_atomic_store(&PART[((size_t)(layer * 2 + g) * 128 + w) * 64 + m], run,
                               __ATOMIC_RELAXED, AGENT);
        }

        // ---------- barrier A (layer-local, flag-based, fence-free) ----------
        __syncthreads();   // implicit vmcnt(0): all waves' sc1 stores at coherence point
        if (tid == 0)
            __hip_atomic_store(&FA[wg * 16], s + 1, __ATOMIC_RELAXED, AGENT);
        if (tid < 128) {
            const int* fp = &FA[(layer * 128 + tid) * 16];
            while (__hip_atomic_load(fp, __ATOMIC_RELAXED, AGENT) < s + 1) {}
        }
        __syncthreads();

        if (active) {
            // global prefix/total, half-split across the 4 waves (sc1 loads)
            int g = pr4 & 1, half = pr4 >> 1;
            const float* pp = PART + ((size_t)(layer * 2 + g) * 128 + half * 64) * 64 + m_u;
            float pref = 0.f, tot = 0.f;
            int wrel = w - half * 64;
#pragma unroll 16
            for (int w2 = 0; w2 < 64; ++w2) {
                float v = __hip_atomic_load(&pp[(size_t)w2 * 64], __ATOMIC_RELAXED, AGENT);
                tot += v;
                pref += (w2 < wrel) ? v : 0.f;
            }
            float* q = sPfx + ((size_t)(m_u * 2 + g) * 2 + half) * 2;
            q[0] = pref; q[1] = tot;
        }
        __syncthreads();
        if (active && tid < 128) {
            int g = tid >> 6, m = tid & 63;
            float* q = sPfx + (size_t)(m * 2 + g) * 4;
            sScl[m * 4 + g * 2]     = q[0] + q[2];
            sScl[m * 4 + g * 2 + 1] = 1.0f / (q[1] + q[3]);
        }
        __syncthreads();

        if (active) {
            // ---------- gate math + state update (2 cols/thread) ----------
            float pf = sScl[m_u * 4 + 0], rf = sScl[m_u * 4 + 1];
            float pi = sScl[m_u * 4 + 2], ri = sScl[m_u * 4 + 3];
            int zb = m_u * 49;
            float cc[2] = {c0, c1}, hh[2];
#pragma unroll
            for (int q = 0; q < 2; ++q) {
                int jj = pr4 * 2 + q;
                float zi = sZ[zb + jj];
                float zf = sZ[zb + 8 + jj];
                float zg = sZ[zb + 16 + jj];
                float zo = sZ[zb + 24 + jj];
                float cft = sZ[zb + 32 + jj];
                float cit = sZ[zb + 40 + jj];
                float ftil = (pf + cft) * rf;
                float itil = 1.0f - (pi + cit) * ri;
                float om = ftil * itil;
                float fi = fast_sigmoid(zf);
                float ii = fast_sigmoid(zi);
                float oo = fast_sigmoid(zo);
                float ch = fast_tanh(zg);
                float fh = fi * om + (ftil - om);
                float ih = ii * om + (itil - om);
                float cn = fh * cc[q] + ih * ch;
                cc[q] = cn;
                hh[q] = oo * fast_tanh(cn);
            }
            c0 = cc[0]; c1 = cc[1];

            // publish h as A-fragments (fp16, sc1 write-through)
            int jfull = j0 + pr4 * 2;
            int ktp = jfull >> 5;
            int quad = (jfull >> 3) & 3;
            int i0 = jfull & 7;
            f16* HP = layer ? (H1P + (size_t)((s + 1) & 1) * 65536)
                            : (H0P + (size_t)(s % 3) * 65536);
            union { f16x2 h; int i; } hu;
            hu.h[0] = (f16)hh[0]; hu.h[1] = (f16)hh[1];
            __hip_atomic_store(
                (int*)(HP + ((size_t)(ktp * 4 + (m_u >> 4)) * 64 + (quad * 16 + (m_u & 15))) * 8 + i0),
                hu.i, __ATOMIC_RELAXED, AGENT);

            if (layer)
                *(float2*)(out + (size_t)t * 65536 + (size_t)m_u * 1024 + jfull) = make_float2(hh[0], hh[1]);
            if (t == 255) {
                *(float2*)(out + 16777216 + (size_t)layer * 65536 + (size_t)m_u * 1024 + jfull) = make_float2(hh[0], hh[1]);
                *(float2*)(out + 16908288 + (size_t)layer * 65536 + (size_t)m_u * 1024 + jfull) = make_float2(cc[0], cc[1]);
            }
        }

        // ---------- barrier B (split by layer, pipeline slack, fence-free) ----------
        if (s < 256) {
            __syncthreads();   // drains all waves' h sc1 stores
            if (tid == 0)
                __hip_atomic_store(&FB[wg * 16], s + 1, __ATOMIC_RELAXED, AGENT);
            if (layer == 0) {
                if (tid < 128) {
                    const int* fp = &FB[tid * 16];
                    while (__hip_atomic_load(fp, __ATOMIC_RELAXED, AGENT) < s + 1) {}
                } else {
                    // anti-overwrite: layer1 must have finished GEMM of step s-1
                    const int* fp = &FA[tid * 16];
                    while (__hip_atomic_load(fp, __ATOMIC_RELAXED, AGENT) < s) {}
                }
            } else {
                const int* fp = &FB[tid * 16];
                while (__hip_atomic_load(fp, __ATOMIC_RELAXED, AGENT) < s + 1) {}
            }
            __syncthreads();
        }
    }
}

// ---------------- launch ----------------
extern "C" void kernel_launch(void* const* d_in, const int* in_sizes, int n_in,
                              void* d_out, int out_size, void* d_ws, size_t ws_size,
                              hipStream_t stream) {
    const float* x  = (const float*)d_in[0];
    const float* W0 = (const float*)d_in[1];
    const float* b0 = (const float*)d_in[2];
    const float* W1 = (const float*)d_in[3];
    const float* b1 = (const float*)d_in[4];
    float* out = (float*)d_out;

    char* ws = (char*)d_ws;
    f16* WB0    = (f16*)(ws + 0);           // 18874368
    f16* WB1    = (f16*)(ws + 18874368);    // 12582912
    f16* WS1    = (f16*)(ws + 31457280);    // 12582912
    f16* XP     = (f16*)(ws + 44040192);    // 16777216
    f16* H0P    = (f16*)(ws + 60817408);    // 3 x 131072
    f16* H1P    = (f16*)(ws + 61210624);    // 2 x 131072
    float* PART = (float*)(ws + 61472768);  // 131072
    int* FLAGS  = (int*)(ws + 61603840);    // 32768

    hipMemsetAsync(H0P, 0, 393216, stream);
    hipMemsetAsync(H1P, 0, 262144, stream);
    hipMemsetAsync(FLAGS, 0, 32768, stream);

    {   int n = 128 * 3 * 48 * 64;
        onlstm_pack_w<<<(n + 255) / 256, 256, 0, stream>>>(W0, WB0, 48, 0); }
    {   int n = 128 * 3 * 32 * 64;
        onlstm_pack_w<<<(n + 255) / 256, 256, 0, stream>>>(W1, WB1, 32, 1024); }
    {   int n = 128 * 3 * 32 * 64;
        onlstm_pack_w<<<(n + 255) / 256, 256, 0, stream>>>(W1, WS1, 32, 0); }
    {   int n = 256 * 16 * 4 * 64;
        onlstm_pack_x<<<(n + 255) / 256, 256, 0, stream>>>(x, XP); }

    const int smem_bytes = 163328;
    hipFuncSetAttribute((const void*)onlstm_main,
                        hipFuncAttributeMaxDynamicSharedMemorySize, smem_bytes);
    onlstm_main<<<NWG, 256, smem_bytes, stream>>>(WB0, WB1, WS1, XP, H0P, H1P,
                                                  PART, FLAGS, b0, b1, out);
}